// Round 2
// baseline (121.710 us; speedup 1.0000x reference)
//
#include <hip/hip_runtime.h>

// dqn MLP: 8 -> 5 -> 5 -> 5 -> 5 -> 5 -> 4, fp32.
// layer0: linear only; layers 1-4: linear+relu; layer5: linear+relu.
// BATCH = 2,097,152 rows. Memory-bound streaming kernel.
//
// R1: 4 rows per thread (rows strided by total-thread-count so every
// global load/store stays lane-coalesced). 8 float4 loads issued up
// front per thread -> 4x memory-level parallelism vs R0; weight
// scalar-loads amortized over 4 rows; 4 independent FMA chains for ILP.

#define IN_DIM 8
#define HID 5
#define OUT_DIM 4
#define ROWS 4

__global__ __launch_bounds__(256) void dqn_mlp_kernel(
    const float* __restrict__ x,
    const float* __restrict__ W0, const float* __restrict__ b0,
    const float* __restrict__ W1, const float* __restrict__ b1,
    const float* __restrict__ W2, const float* __restrict__ b2,
    const float* __restrict__ W3, const float* __restrict__ b3,
    const float* __restrict__ W4, const float* __restrict__ b4,
    const float* __restrict__ W5, const float* __restrict__ b5,
    float* __restrict__ out, int batch)
{
    const int total = batch / ROWS;                    // threads needed
    const int t = blockIdx.x * blockDim.x + threadIdx.x;
    if (t >= total) return;

    const float4* __restrict__ xv = reinterpret_cast<const float4*>(x);
    float4* __restrict__ ov4 = reinterpret_cast<float4*>(out);

    // Issue all 8 loads first (4 rows x 2 float4) for max MLP.
    float4 xa[ROWS], xb[ROWS];
    #pragma unroll
    for (int r = 0; r < ROWS; ++r) {
        const int row = t + r * total;                 // lane-coalesced
        xa[r] = xv[2 * row];
        xb[r] = xv[2 * row + 1];
    }

    const float* __restrict__ Ws[4] = {W1, W2, W3, W4};
    const float* __restrict__ bs[4] = {b1, b2, b3, b4};

    float h[ROWS][HID];

    // input layer: linear only (no relu)
    #pragma unroll
    for (int r = 0; r < ROWS; ++r) {
        const float xin[IN_DIM] = {xa[r].x, xa[r].y, xa[r].z, xa[r].w,
                                   xb[r].x, xb[r].y, xb[r].z, xb[r].w};
        #pragma unroll
        for (int j = 0; j < HID; ++j) {
            float s = b0[j];
            #pragma unroll
            for (int k = 0; k < IN_DIM; ++k)
                s = fmaf(xin[k], W0[j * IN_DIM + k], s);
            h[r][j] = s;
        }
    }

    // hidden layers 1..4: linear + relu (weights loaded once, used ROWS x)
    #pragma unroll
    for (int l = 0; l < 4; ++l) {
        #pragma unroll
        for (int r = 0; r < ROWS; ++r) {
            float g[HID];
            #pragma unroll
            for (int j = 0; j < HID; ++j) {
                float s = bs[l][j];
                #pragma unroll
                for (int k = 0; k < HID; ++k)
                    s = fmaf(h[r][k], Ws[l][j * HID + k], s);
                g[j] = fmaxf(s, 0.0f);
            }
            #pragma unroll
            for (int j = 0; j < HID; ++j) h[r][j] = g[j];
        }
    }

    // output layer: linear + relu, store float4 per row
    #pragma unroll
    for (int r = 0; r < ROWS; ++r) {
        float ov[OUT_DIM];
        #pragma unroll
        for (int j = 0; j < OUT_DIM; ++j) {
            float s = b5[j];
            #pragma unroll
            for (int k = 0; k < HID; ++k)
                s = fmaf(h[r][k], W5[j * HID + k], s);
            ov[j] = fmaxf(s, 0.0f);
        }
        ov4[t + r * total] = make_float4(ov[0], ov[1], ov[2], ov[3]);
    }
}

extern "C" void kernel_launch(void* const* d_in, const int* in_sizes, int n_in,
                              void* d_out, int out_size, void* d_ws, size_t ws_size,
                              hipStream_t stream) {
    const float* x  = (const float*)d_in[0];
    const float* W0 = (const float*)d_in[1];
    const float* b0 = (const float*)d_in[2];
    const float* W1 = (const float*)d_in[3];
    const float* b1 = (const float*)d_in[4];
    const float* W2 = (const float*)d_in[5];
    const float* b2 = (const float*)d_in[6];
    const float* W3 = (const float*)d_in[7];
    const float* b3 = (const float*)d_in[8];
    const float* W4 = (const float*)d_in[9];
    const float* b4 = (const float*)d_in[10];
    const float* W5 = (const float*)d_in[11];
    const float* b5 = (const float*)d_in[12];
    float* out = (float*)d_out;

    int batch = in_sizes[0] / IN_DIM;          // 2,097,152
    int total = batch / ROWS;                  // 524,288 threads
    int block = 256;
    int grid = (total + block - 1) / block;    // 2048 blocks
    dqn_mlp_kernel<<<grid, block, 0, stream>>>(
        x, W0, b0, W1, b1, W2, b2, W3, b3, W4, b4, W5, b5, out, batch);
}